// Round 1
// baseline (11.173 us; speedup 1.0000x reference)
//
#include <hip/hip_runtime.h>

// MPSELoss: loss = sum_b [ N*sum_i d_bi^2 - (sum_i d_bi)^2 ] / (B * N*(N-1)/2)
// where d = outputs - targets. Derived from sum_{i<j}(d_i-d_j)^2 identity.

#define BB 32
#define NN 2048

__global__ void __launch_bounds__(256) mpse_row_partial(const float* __restrict__ outs,
                                                        const float* __restrict__ tgts,
                                                        float* __restrict__ ws) {
    const int row = blockIdx.x;
    const int t = threadIdx.x;
    const float4* o4 = reinterpret_cast<const float4*>(outs + (size_t)row * NN);
    const float4* g4 = reinterpret_cast<const float4*>(tgts + (size_t)row * NN);

    float s1 = 0.f, s2 = 0.f;
    // 2048 floats = 512 float4 per row; 256 threads -> 2 float4 each, coalesced.
#pragma unroll
    for (int k = 0; k < 2; ++k) {
        float4 a = o4[t + k * 256];
        float4 b = g4[t + k * 256];
        float d0 = a.x - b.x;
        float d1 = a.y - b.y;
        float d2 = a.z - b.z;
        float d3 = a.w - b.w;
        s1 += (d0 + d1) + (d2 + d3);
        s2 += (d0 * d0 + d1 * d1) + (d2 * d2 + d3 * d3);
    }

    // wave64 butterfly reduce
#pragma unroll
    for (int off = 32; off >= 1; off >>= 1) {
        s1 += __shfl_xor(s1, off);
        s2 += __shfl_xor(s2, off);
    }

    __shared__ float sh1[4];
    __shared__ float sh2[4];
    const int wave = t >> 6;
    if ((t & 63) == 0) {
        sh1[wave] = s1;
        sh2[wave] = s2;
    }
    __syncthreads();
    if (t == 0) {
        float S1 = (sh1[0] + sh1[1]) + (sh1[2] + sh1[3]);
        float S2 = (sh2[0] + sh2[1]) + (sh2[2] + sh2[3]);
        // combine in double: N*S2 ~ 8.4e6, S1^2 ~ 4e3 — double kills rounding here
        ws[row] = (float)((double)NN * (double)S2 - (double)S1 * (double)S1);
    }
}

__global__ void __launch_bounds__(64) mpse_final_reduce(const float* __restrict__ ws,
                                                        float* __restrict__ out) {
    const int t = threadIdx.x;
    float v = (t < BB) ? ws[t] : 0.f;
#pragma unroll
    for (int off = 32; off >= 1; off >>= 1) {
        v += __shfl_xor(v, off);
    }
    if (t == 0) {
        const double count = (double)BB * ((double)NN * (double)(NN - 1) * 0.5);
        out[0] = (float)((double)v / count);
    }
}

extern "C" void kernel_launch(void* const* d_in, const int* in_sizes, int n_in,
                              void* d_out, int out_size, void* d_ws, size_t ws_size,
                              hipStream_t stream) {
    const float* outs = (const float*)d_in[0];
    const float* tgts = (const float*)d_in[1];
    float* ws = (float*)d_ws;   // 32 floats of scratch
    float* out = (float*)d_out; // 1 float

    mpse_row_partial<<<dim3(BB), dim3(256), 0, stream>>>(outs, tgts, ws);
    mpse_final_reduce<<<dim3(1), dim3(64), 0, stream>>>(ws, out);
}

// Round 2
// 10.098 us; speedup vs baseline: 1.1064x; 1.1064x over previous
//
#include <hip/hip_runtime.h>

// MPSELoss fused single-dispatch:
// loss = sum_b [ N*sum_i d_bi^2 - (sum_i d_bi)^2 ] / (B * N*(N-1)/2),  d = outputs - targets
// One workgroup of 1024 threads: 32 threads per row (B=32 rows), shuffle-reduce
// per row, LDS for the 32 per-row partials, thread 0 does the final fixed-order sum.

#define BB 32
#define NN 2048

__global__ void __launch_bounds__(1024) mpse_fused(const float* __restrict__ outs,
                                                   const float* __restrict__ tgts,
                                                   float* __restrict__ out) {
    const int t = threadIdx.x;
    const int row = t >> 5;        // 0..31, one 32-thread group per row
    const int l = t & 31;          // lane within group

    const float4* o4 = reinterpret_cast<const float4*>(outs + (size_t)row * NN);
    const float4* g4 = reinterpret_cast<const float4*>(tgts + (size_t)row * NN);

    float s1 = 0.f, s2 = 0.f;
    // 2048 floats/row = 512 float4; 32 threads -> 16 float4 each, 512B coalesced segments
#pragma unroll
    for (int j = 0; j < 16; ++j) {
        float4 a = o4[l + j * 32];
        float4 b = g4[l + j * 32];
        float d0 = a.x - b.x;
        float d1 = a.y - b.y;
        float d2 = a.z - b.z;
        float d3 = a.w - b.w;
        s1 += (d0 + d1) + (d2 + d3);
        s2 += (d0 * d0 + d1 * d1) + (d2 * d2 + d3 * d3);
    }

    // reduce within the 32-thread group (xor offsets stay inside the 32-lane half)
#pragma unroll
    for (int off = 16; off >= 1; off >>= 1) {
        s1 += __shfl_xor(s1, off);
        s2 += __shfl_xor(s2, off);
    }

    __shared__ double sh[BB];
    if (l == 0) {
        // per-row value: N*S2 - S1^2, combined in double (no cancellation risk)
        sh[row] = (double)NN * (double)s2 - (double)s1 * (double)s1;
    }
    __syncthreads();

    if (t == 0) {
        double acc = 0.0;
#pragma unroll
        for (int r = 0; r < BB; ++r) acc += sh[r];
        const double count = (double)BB * ((double)NN * (double)(NN - 1) * 0.5);
        out[0] = (float)(acc / count);
    }
}

extern "C" void kernel_launch(void* const* d_in, const int* in_sizes, int n_in,
                              void* d_out, int out_size, void* d_ws, size_t ws_size,
                              hipStream_t stream) {
    const float* outs = (const float*)d_in[0];
    const float* tgts = (const float*)d_in[1];
    float* out = (float*)d_out; // 1 float

    mpse_fused<<<dim3(1), dim3(1024), 0, stream>>>(outs, tgts, out);
}